// Round 1
// 753.888 us; speedup vs baseline: 1.3429x; 1.3429x over previous
//
#include <hip/hip_runtime.h>

#define SEQ 365
#define BS  2048
#define HS  64
#define IND 32
#define XXC 5
#define NROWS (BS * SEQ)          // 747520
#define PRE_STRIDE 192
#define WS_NEEDED ((size_t)NROWS * PRE_STRIDE * sizeof(float))  // ~574 MB

typedef float f32x2 __attribute__((ext_vector_type(2)));

// packed fp32 FMA: acc = a*b + acc (componentwise), one VALU issue for 2 FMAs
#define PKFMA(acc, a, b) asm("v_pk_fma_f32 %0, %1, %2, %0" : "+v"(acc) : "v"(a), "v"(b))

__device__ __forceinline__ float rcp_(float x) { return __builtin_amdgcn_rcpf(x); }
__device__ __forceinline__ float sig_(float x) { return rcp_(1.0f + __expf(-x)); }
__device__ __forceinline__ float tanh_(float x) { return 1.0f - 2.0f * rcp_(1.0f + __expf(2.0f * x)); }
__device__ __forceinline__ float bcast_(float v, int lane) {
    return __int_as_float(__builtin_amdgcn_readlane(__float_as_int(v), lane));
}

// ---------------- Phase 1: pregates (no recurrence, pure batch) ----------
// pre[r][0:64]   = bias0 + x_r @ Wx[:, 0:64]
// pre[r][64:128] = bias3 + x_r @ Wx[:, 64:128]
// pre[r][128:192]= bias4 + td_r*wtB + x_r @ Wx[:, 128:192]
// Restructured: LDS-staged x tile (coalesced float4 loads, double-buffered),
// uniform-address ds_read_b64 pair broadcast + v_pk_fma_f32.
#define PG_RPB   64               // rows per block
#define PG_CHUNK 16               // rows staged per LDS buffer
#define PG_NCH   (PG_RPB / PG_CHUNK)

__global__ __launch_bounds__(64, 2)
void pregate_kernel(const float* __restrict__ x_for_h,
                    const float* __restrict__ td_in,
                    const float* __restrict__ Wx,    // [32][192]
                    const float* __restrict__ Wt,    // [128]
                    const float* __restrict__ bias,  // [320]
                    float* __restrict__ pre)
{
    __shared__ __align__(16) float xs[2][PG_CHUNK * IND];  // 2 x 2KB
    __shared__ float tds[2][PG_CHUNK];
    const int l = threadIdx.x;

    // weight pairs along k: wx?p[m] = (W[2m][col], W[2m+1][col])
    f32x2 wx0p[16], wxcp[16], wxop[16];
#pragma unroll
    for (int m = 0; m < 16; ++m) {
        wx0p[m] = {Wx[(2 * m) * 192 + l],       Wx[(2 * m + 1) * 192 + l]};
        wxcp[m] = {Wx[(2 * m) * 192 + 64 + l],  Wx[(2 * m + 1) * 192 + 64 + l]};
        wxop[m] = {Wx[(2 * m) * 192 + 128 + l], Wx[(2 * m + 1) * 192 + 128 + l]};
    }
    const float wtB = Wt[64 + l];
    const float b0i = bias[l], b3i = bias[192 + l], b4i = bias[256 + l];

    const int r0 = blockIdx.x * PG_RPB;

    {   // stage chunk 0 (16 rows x 32 floats = 512 floats, two coalesced 1KB loads)
        const float4* xg = (const float4*)(x_for_h + (size_t)r0 * IND);
        float4 s0 = xg[l];
        float4 s1 = xg[64 + l];
        float tdl = (l < PG_CHUNK) ? td_in[r0 + l] : 0.0f;
        *(float4*)&xs[0][l * 4] = s0;
        *(float4*)&xs[0][256 + l * 4] = s1;
        if (l < PG_CHUNK) tds[0][l] = tdl;
    }

    for (int cc = 0; cc < PG_NCH; ++cc) {
        const int cur = cc & 1, nxt = cur ^ 1;
        // issue next chunk's global loads early (latency hides under compute)
        const int cn = (cc + 1 < PG_NCH) ? cc + 1 : cc;
        const float4* xgn = (const float4*)(x_for_h + (size_t)(r0 + cn * PG_CHUNK) * IND);
        float4 n0 = xgn[l];
        float4 n1 = xgn[64 + l];
        float ntd = (l < PG_CHUNK) ? td_in[r0 + cn * PG_CHUNK + l] : 0.0f;

        const int rbase = r0 + cc * PG_CHUNK;
#pragma unroll
        for (int i = 0; i < PG_CHUNK; ++i) {
            const f32x2* xp = (const f32x2*)&xs[cur][i * IND];  // uniform addr -> broadcast
            f32x2 ai = {b0i, 0.0f};
            f32x2 ac = {b3i, 0.0f};
            f32x2 ao = {fmaf(tds[cur][i], wtB, b4i), 0.0f};
#pragma unroll
            for (int m = 0; m < 16; ++m) {
                f32x2 xv = xp[m];
                PKFMA(ai, xv, wx0p[m]);
                PKFMA(ac, xv, wxcp[m]);
                PKFMA(ao, xv, wxop[m]);
            }
            float* p = pre + (size_t)(rbase + i) * PRE_STRIDE;
            p[l]       = ai.x + ai.y;
            p[64 + l]  = ac.x + ac.y;
            p[128 + l] = ao.x + ao.y;
        }
        if (cc + 1 < PG_NCH) {  // write-late half of the async stage
            *(float4*)&xs[nxt][l * 4] = n0;
            *(float4*)&xs[nxt][256 + l * 4] = n1;
            if (l < PG_CHUNK) tds[nxt][l] = ntd;
        }
    }
}

// ---------------- Phase 2: recurrence only -------------------------------
// h broadcast via uniform-address ds_read_b64 from ping-pong LDS (off-VALU),
// matmul via v_pk_fma_f32 (96 issues for 192 MACs), weights pinned to arch
// VGPRs by the asm "v" constraints (old kernel: VGPR_Count=112 => weights
// lived in AGPRs with per-use v_accvgpr_read copies).
__global__ __launch_bounds__(64, 2)
void recur_kernel(const float* __restrict__ pre,
                  const float* __restrict__ x_for_x,
                  const float* __restrict__ td_in,
                  const float* __restrict__ Wxm,   // [5][128]
                  const float* __restrict__ Wh,    // [64][192]
                  const float* __restrict__ Wt1,   // [64]
                  const float* __restrict__ Wt,    // [128]
                  const float* __restrict__ bias,  // [320]
                  float* __restrict__ out)
{
    __shared__ __align__(16) float hbuf[2][HS];
    const int b = blockIdx.x;
    const int j = threadIdx.x;

    // Wh pairs along k: whp?[m] = (Wh[2m][col], Wh[2m+1][col]) -> 192 VGPRs
    f32x2 whp0[32], whpc[32], whpo[32];
#pragma unroll
    for (int m = 0; m < 32; ++m) {
        whp0[m] = {Wh[(2 * m) * 192 + j],       Wh[(2 * m + 1) * 192 + j]};
        whpc[m] = {Wh[(2 * m) * 192 + 64 + j],  Wh[(2 * m + 1) * 192 + 64 + j]};
        whpo[m] = {Wh[(2 * m) * 192 + 128 + j], Wh[(2 * m + 1) * 192 + 128 + j]};
    }
    float wm1[XXC], wm2[XXC];
#pragma unroll
    for (int k = 0; k < XXC; ++k) {
        wm1[k] = Wxm[k * 128 + j];
        wm2[k] = Wxm[k * 128 + 64 + j];
    }
    const float wt1j = fminf(Wt1[j], 0.0f);
    const float wtA  = Wt[j];
    const float b1i = bias[64 + j], b2i = bias[128 + j];

    hbuf[0][j] = 0.0f;   // t=0 reads buffer 0; single wave + in-order LDS => no barrier
    float h = 0.0f, c = 0.0f;

    const float* prep = pre + (size_t)b * SEQ * PRE_STRIDE;
    const float* xxb  = x_for_x + (size_t)b * SEQ * XXC;   // wave-uniform
    const float* tdp  = td_in + (size_t)b * SEQ;           // wave-uniform
    float* outp = out + (size_t)b * SEQ * HS + j;

    // pre row for t=0 (prefetched one step ahead inside the loop)
    float pi = prep[j], pc = prep[64 + j], po = prep[128 + j];

    for (int t = 0; t < SEQ; ++t) {
        const int cur = t & 1;

        // issue next-step pre prefetch first (HBM ~900cy; full step of cover)
        const int tn = (t + 1 < SEQ) ? t + 1 : t;
        const float* pn = prep + (size_t)tn * PRE_STRIDE;
        const float npi = pn[j], npc = pn[64 + j], npo = pn[128 + j];

        // current-step uniform scalars (covered by the matmul below)
        const float* xq = xxb + (size_t)t * XXC;
        float xxv[XXC];
#pragma unroll
        for (int k = 0; k < XXC; ++k) xxv[k] = xq[k];
        const float td = tdp[t];

        // h @ Wh via LDS broadcast pairs + packed fma, 2 chains/gate for ILP
        const f32x2* hp = (const f32x2*)hbuf[cur];
        f32x2 a_i0 = {0.0f, 0.0f}, a_i1 = {0.0f, 0.0f};
        f32x2 a_c0 = {0.0f, 0.0f}, a_c1 = {0.0f, 0.0f};
        f32x2 a_o0 = {0.0f, 0.0f}, a_o1 = {0.0f, 0.0f};
#pragma unroll
        for (int m = 0; m < 32; m += 2) {
            f32x2 h0 = hp[m];
            f32x2 h1 = hp[m + 1];
            PKFMA(a_i0, h0, whp0[m]);  PKFMA(a_i1, h1, whp0[m + 1]);
            PKFMA(a_c0, h0, whpc[m]);  PKFMA(a_c1, h1, whpc[m + 1]);
            PKFMA(a_o0, h0, whpo[m]);  PKFMA(a_o1, h1, whpo[m + 1]);
        }
        const float ai = (a_i0.x + a_i0.y) + (a_i1.x + a_i1.y) + pi;
        const float ac = (a_c0.x + a_c0.y) + (a_c1.x + a_c1.y) + pc;
        const float ao = (a_o0.x + a_o0.y) + (a_o1.x + a_o1.y) + po;

        float am1 = b1i, am2 = b2i;
#pragma unroll
        for (int k = 0; k < XXC; ++k) {
            am1 = fmaf(xxv[k], wm1[k], am1);
            am2 = fmaf(xxv[k], wm2[k], am2);
        }

        const float i_t  = sig_(ai);
        const float t1   = sig_(am1 + tanh_(td * wt1j));
        const float t2   = sig_(am2 + tanh_(td * wtA));
        const float capp = tanh_(ac);
        const float it1  = i_t * t1;
        const float ctl  = sig_(fmaf(it1, capp - c, c));           // sigmoid(c + i*t1*(capp-c))
        const float cn   = sig_(fmaf(i_t, fmaf(t2, capp, -c), c)); // sigmoid(c + i*(t2*capp-c))
        const float o_t  = sig_(ao);                               // td*wtB folded in phase 1
        const float hn   = o_t + tanh_(ctl);

        outp[(size_t)t * HS] = hn;
        hbuf[cur ^ 1][j] = hn;   // ping-pong; in-order DS makes this race-free
        h = hn; c = cn;
        pi = npi; pc = npc; po = npo;
    }

    float* hT = out + (size_t)BS * SEQ * HS;
    float* cT = hT + (size_t)BS * HS;
    hT[(size_t)b * HS + j] = h;
    cT[(size_t)b * HS + j] = c;
}

// ---------------- Fallback: proven monolithic R1 kernel ------------------
__global__ __launch_bounds__(64, 1)
void tlstm_mono(const float* __restrict__ x_for_h,
                const float* __restrict__ x_for_x,
                const float* __restrict__ td_in,
                const float* __restrict__ Wx,
                const float* __restrict__ Wxm,
                const float* __restrict__ Wh,
                const float* __restrict__ Wt1,
                const float* __restrict__ Wt,
                const float* __restrict__ bias,
                float* __restrict__ out)
{
    const int b = blockIdx.x;
    const int j = threadIdx.x;
    float wx0[IND], wxc[IND], wxo[IND];
#pragma unroll
    for (int k = 0; k < IND; ++k) {
        wx0[k] = Wx[k * 192 + j];
        wxc[k] = Wx[k * 192 + 64 + j];
        wxo[k] = Wx[k * 192 + 128 + j];
    }
    float wh0[HS], whc[HS], who[HS];
#pragma unroll
    for (int k = 0; k < HS; ++k) {
        wh0[k] = Wh[k * 192 + j];
        whc[k] = Wh[k * 192 + 64 + j];
        who[k] = Wh[k * 192 + 128 + j];
    }
    float wm1[XXC], wm2[XXC];
#pragma unroll
    for (int k = 0; k < XXC; ++k) {
        wm1[k] = Wxm[k * 128 + j];
        wm2[k] = Wxm[k * 128 + 64 + j];
    }
    const float wt1j = fminf(Wt1[j], 0.0f);
    const float wtA = Wt[j], wtB = Wt[64 + j];
    const float b0i = bias[j], b1i = bias[64 + j], b2i = bias[128 + j];
    const float b3i = bias[192 + j], b4i = bias[256 + j];

    float h = 0.0f, c = 0.0f;
    const float* xh  = x_for_h + (size_t)b * SEQ * IND;
    const float* xx  = x_for_x + (size_t)b * SEQ * XXC;
    const float* tdp = td_in + (size_t)b * SEQ;
    float* outp = out + (size_t)b * SEQ * HS + j;

    for (int t = 0; t < SEQ; ++t) {
        float ai = b0i, ac = b3i, ao = b4i;
#pragma unroll
        for (int k = 0; k < IND; ++k) {
            const float xv = xh[k];
            ai = fmaf(xv, wx0[k], ai);
            ac = fmaf(xv, wxc[k], ac);
            ao = fmaf(xv, wxo[k], ao);
        }
#pragma unroll
        for (int k = 0; k < HS; ++k) {
            const float hk = bcast_(h, k);
            ai = fmaf(hk, wh0[k], ai);
            ac = fmaf(hk, whc[k], ac);
            ao = fmaf(hk, who[k], ao);
        }
        float am1 = b1i, am2 = b2i;
#pragma unroll
        for (int k = 0; k < XXC; ++k) {
            const float xv = xx[k];
            am1 = fmaf(xv, wm1[k], am1);
            am2 = fmaf(xv, wm2[k], am2);
        }
        const float td = tdp[t];
        const float i_t  = sig_(ai);
        const float t1   = sig_(am1 + tanh_(td * wt1j));
        const float t2   = sig_(am2 + tanh_(td * wtA));
        const float capp = tanh_(ac);
        const float it1  = i_t * t1;
        const float ctl  = sig_(fmaf(it1, capp - c, c));
        const float cn   = sig_(fmaf(i_t, fmaf(t2, capp, -c), c));
        const float o_t  = sig_(fmaf(td, wtB, ao));
        const float hn   = o_t + tanh_(ctl);
        outp[(size_t)t * HS] = hn;
        h = hn; c = cn;
        xh += IND; xx += XXC;
    }
    float* hT = out + (size_t)BS * SEQ * HS;
    float* cT = hT + (size_t)BS * HS;
    hT[(size_t)b * HS + j] = h;
    cT[(size_t)b * HS + j] = c;
}

extern "C" void kernel_launch(void* const* d_in, const int* in_sizes, int n_in,
                              void* d_out, int out_size, void* d_ws, size_t ws_size,
                              hipStream_t stream)
{
    const float* x_for_h = (const float*)d_in[0];
    const float* x_for_x = (const float*)d_in[1];
    const float* TimeDiff = (const float*)d_in[2];
    const float* weights_x = (const float*)d_in[3];
    const float* weights_x_maintained = (const float*)d_in[4];
    const float* weights_h = (const float*)d_in[5];
    const float* weights_t1 = (const float*)d_in[6];
    const float* weights_t = (const float*)d_in[7];
    const float* bias = (const float*)d_in[8];
    float* out = (float*)d_out;

    if (ws_size >= WS_NEEDED) {
        float* pre = (float*)d_ws;
        pregate_kernel<<<NROWS / PG_RPB, 64, 0, stream>>>(x_for_h, TimeDiff,
                                                          weights_x, weights_t, bias, pre);
        recur_kernel<<<BS, 64, 0, stream>>>(pre, x_for_x, TimeDiff,
                                            weights_x_maintained, weights_h,
                                            weights_t1, weights_t, bias, out);
    } else {
        tlstm_mono<<<BS, 64, 0, stream>>>(x_for_h, x_for_x, TimeDiff,
                                          weights_x, weights_x_maintained, weights_h,
                                          weights_t1, weights_t, bias, out);
    }
}